// Round 8
// baseline (460.897 us; speedup 1.0000x reference)
//
#include <hip/hip_runtime.h>
#include <stdint.h>

#define DD 1024
#define TT 2048
#define BBATCH 8
#define MM (BBATCH*TT)   // 16384 rows

typedef unsigned short u16;
typedef unsigned int   u32;

typedef __attribute__((ext_vector_type(8))) __bf16 bf16x8;
typedef __attribute__((ext_vector_type(4))) float  floatx4;
typedef __attribute__((ext_vector_type(4))) unsigned short u16x4;
typedef __attribute__((ext_vector_type(8))) unsigned short u16x8;
typedef __attribute__((ext_vector_type(4))) unsigned int   u32x4;

__device__ __forceinline__ float b2f(u16 v){
    u32 x = ((u32)v) << 16;
    return __builtin_bit_cast(float, x);
}
__device__ __forceinline__ u16 f2b(float f){
    u32 u = __builtin_bit_cast(u32, f);
    u32 r = (u + 0x7fffu + ((u >> 16) & 1u)) >> 16;
    return (u16)r;
}
__device__ __forceinline__ float sigf(float x){
    return 1.0f / (1.0f + __expf(-x));
}
__device__ __forceinline__ float tanhfast(float x){
    float e = __expf(2.0f * x);          // inf for big x -> 1.0 (correct limit)
    return 1.0f - 2.0f / (e + 1.0f);
}

// async global->LDS, 16B per lane. LDS dest = wave-uniform base + lane*16.
__device__ __forceinline__ void g2l16(const u16* g, u16* l){
    __builtin_amdgcn_global_load_lds(
        (const __attribute__((address_space(1))) u32*)g,
        (__attribute__((address_space(3))) u32*)l, 16, 0, 0);
}

__device__ __forceinline__ u32 lds_u32(const u16* p){
    return (u32)(size_t)(const __attribute__((address_space(3))) u16*)p;
}

// inline-asm LDS read: compiler does not model the load, so explicit
// lgkmcnt(0)+sched_barrier(0) fencing is mandatory before consuming (rule #18).
template<int OFF>
__device__ __forceinline__ bf16x8 dsr(u32 addr){
    u32x4 d;
    asm volatile("ds_read_b128 %0, %1 offset:%2" : "=v"(d) : "v"(addr), "i"(OFF));
    return __builtin_bit_cast(bf16x8, d);
}

// kk (k-half) lives in separate base registers a0/a1: the bank swizzle XOR
// occupies byte bits 4-6, which an immediate +64 offset would corrupt.
template<int BASE>
__device__ __forceinline__ void rd_a8(bf16x8 (&arr)[8], u32 a0, u32 a1){
    arr[0]=dsr<BASE+0>(a0);    arr[1]=dsr<BASE+0>(a1);
    arr[2]=dsr<BASE+2048>(a0); arr[3]=dsr<BASE+2048>(a1);
    arr[4]=dsr<BASE+4096>(a0); arr[5]=dsr<BASE+4096>(a1);
    arr[6]=dsr<BASE+6144>(a0); arr[7]=dsr<BASE+6144>(a1);
}
template<int BASE>
__device__ __forceinline__ void rd_b4(bf16x8 (&arr)[4], u32 a0, u32 a1){
    arr[0]=dsr<BASE+0>(a0);    arr[1]=dsr<BASE+0>(a1);
    arr[2]=dsr<BASE+2048>(a0); arr[3]=dsr<BASE+2048>(a1);
}

__device__ __forceinline__ void load4bf(const u16* p, float* o){
    u16x4 v = *(const u16x4*)p;
    o[0] = b2f(v.x); o[1] = b2f(v.y); o[2] = b2f(v.z); o[3] = b2f(v.w);
}

__device__ __forceinline__ void wave_reduce2(float& a, float& b){
    #pragma unroll
    for (int m = 32; m; m >>= 1){
        a += __shfl_xor(a, m, 64);
        b += __shfl_xor(b, m, 64);
    }
}

// safe for repeated use: leading barrier protects red from the previous round
__device__ __forceinline__ void block_reduce2(float& a, float& b, float* red, int tid){
    #pragma unroll
    for (int off = 32; off; off >>= 1){
        a += __shfl_down(a, off, 64);
        b += __shfl_down(b, off, 64);
    }
    __syncthreads();
    if ((tid & 63) == 0){ red[tid >> 6] = a; red[4 + (tid >> 6)] = b; }
    __syncthreads();
    a = red[0] + red[1] + red[2] + red[3];
    b = red[4] + red[5] + red[6] + red[7];
}

// ---------------- weight transpose: 6 x [1024,1024] fp32 -> bf16 [N,K] ----------------
__global__ __launch_bounds__(256) void transpose_w(
    const float* __restrict__ s0, const float* __restrict__ s1, const float* __restrict__ s2,
    const float* __restrict__ s3, const float* __restrict__ s4, const float* __restrict__ s5,
    u16* __restrict__ dst_base)
{
    __shared__ u16 tile[32][33];
    const float* srcs[6] = {s0, s1, s2, s3, s4, s5};
    const int z = blockIdx.z;
    const float* src = srcs[z];
    u16* dst = dst_base + (size_t)z * (DD * (size_t)DD);
    const int tx = threadIdx.x, ty = threadIdx.y;
    const int x = blockIdx.x * 32 + tx;
    #pragma unroll
    for (int i = 0; i < 4; i++){
        int y = blockIdx.y * 32 + ty + i * 8;
        tile[ty + i * 8][tx] = f2b(src[(size_t)y * DD + x]);
    }
    __syncthreads();
    const int x2 = blockIdx.y * 32 + tx;
    #pragma unroll
    for (int i = 0; i < 4; i++){
        int y2 = blockIdx.x * 32 + ty + i * 8;
        dst[(size_t)y2 * DD + x2] = tile[tx][ty + i * 8];
    }
}

// ---------------- conv-weight transpose: [1024,3] -> [3][1024], 3 streams ----------------
__global__ __launch_bounds__(256) void prep_wc(
    const float* __restrict__ w0, const float* __restrict__ w1, const float* __restrict__ w2,
    float* __restrict__ wcT)
{
    const float* srcs[3] = {w0, w1, w2};
    const int s = blockIdx.x / 3, tap = blockIdx.x % 3;
    #pragma unroll
    for (int i = 0; i < 4; i++){
        int d = threadIdx.x + i * 256;
        wcT[(s * 3 + tap) * DD + d] = srcs[s][d * 3 + tap];
    }
}

// ---------------- fused: x -> bf16 copy (xb) + zc_rms(x,g1) -> h; one row per wave ----------------
__global__ __launch_bounds__(256) void prep_rows(
    const float* __restrict__ in, const float* __restrict__ g,
    u16* __restrict__ xb, u16* __restrict__ h)
{
    const int tid = threadIdx.x;
    const int w = tid >> 6, lane = tid & 63;
    const int row = blockIdx.x * 4 + w;
    const int d0 = lane * 16;
    const size_t base = (size_t)row * DD + d0;

    float v[16];
    #pragma unroll
    for (int c = 0; c < 4; c++){
        floatx4 t = *(const floatx4*)(in + base + c * 4);
        v[c*4+0] = t.x; v[c*4+1] = t.y; v[c*4+2] = t.z; v[c*4+3] = t.w;
    }
    u16x8 x0, x1;
    #pragma unroll
    for (int j = 0; j < 8; j++){ x0[j] = f2b(v[j]); x1[j] = f2b(v[8+j]); }
    *(u16x8*)(xb + base)     = x0;
    *(u16x8*)(xb + base + 8) = x1;

    float s1 = 0.f, s2 = 0.f;
    #pragma unroll
    for (int j = 0; j < 16; j++){ s1 += v[j]; s2 += v[j]*v[j]; }
    wave_reduce2(s1, s2);
    const float mu = s1 * (1.0f / DD);
    const float ms = fmaxf(s2 * (1.0f / DD) - mu * mu, 0.0f);
    const float sc = rsqrtf(ms + 1e-8f);

    u16x8 o0, o1;
    #pragma unroll
    for (int j = 0; j < 8; j++)  o0[j] = f2b((v[j]     - mu) * sc * g[d0 + j]);
    #pragma unroll
    for (int j = 0; j < 8; j++)  o1[j] = f2b((v[8 + j] - mu) * sc * g[d0 + 8 + j]);
    *(u16x8*)(h + base)     = o0;
    *(u16x8*)(h + base + 8) = o1;
}

// ---------------- GEMM: C[M,N] = A[M,K](bf16) * W^T[N,K](bf16)^T + bias(fp32) ----------------
// VERIFIED r5 structure (453.9 us total, gemm<0> 161 us, conflicts = 0).
// 256x256 tile, BK=64, 512 thr (8 waves 2Mx4N), per-wave 128x64 out.
// Conflict-free swizzle: phys_byte = logical ^ ((row&7)<<4).
// READ-AHEAD pipeline: each fragment group ds_read one MFMA-quadrant EARLY:
//   PhaseA: [A0,B0 pre-read last tile] q00; read B1; q01; read A1;   VM4+BAR
//   PhaseB: q10; read-ahead A0',B0' (tile t+1, other parity buffer); q11; VM4+BAR
// Staging: PA stages Bh1(t+1), Ah1(t+1); PB stages Ah0(t+2), Bh0(t+2).
// vmcnt(4) at PA-end drains Ah0(t+1),Bh0(t+1); vmcnt(4) at PB-end drains Bh1/Ah1(t+1).
struct GemmPtrs {
    const u16*   A[5];
    const u16*   W[5];     // transposed weights, [N,K] row-major, bf16
    const float* bias[5];
    u16*         out[5];
};

#define BAR()   asm volatile("s_barrier" ::: "memory")
#define LGKM0() asm volatile("s_waitcnt lgkmcnt(0)" ::: "memory")
#define VM4()   asm volatile("s_waitcnt vmcnt(4)" ::: "memory")
#define SB0()   __builtin_amdgcn_sched_barrier(0)
#define PRIO1() __builtin_amdgcn_s_setprio(1)
#define PRIO0() __builtin_amdgcn_s_setprio(0)

template<int IH, int JH>
__device__ __forceinline__ void mm8(floatx4 (&acc)[8][4], const bf16x8 (&af)[8], const bf16x8 (&bf)[4]){
    #pragma unroll
    for (int kk = 0; kk < 2; kk++)
        #pragma unroll
        for (int i = 0; i < 4; i++)
            #pragma unroll
            for (int j = 0; j < 2; j++)
                acc[IH*4+i][JH*2+j] = __builtin_amdgcn_mfma_f32_16x16x32_bf16(
                    af[i*2+kk], bf[j*2+kk], acc[IH*4+i][JH*2+j], 0, 0, 0);
}

template<int MODE>   // 0: store bf16(A*W+bias) ; 1: fp32 epilogue with residual
__global__ __launch_bounds__(512, 2) void gemm_bf16(
    GemmPtrs ptrs, const float* __restrict__ xres, float* __restrict__ dout)
{
    __shared__ alignas(16) u16 lds[65536];        // 128 KB: A 0..64KB, B 64..128KB

    const int z = blockIdx.z;
    const u16*   __restrict__ A    = ptrs.A[z];
    const u16*   __restrict__ W    = ptrs.W[z];
    const float* __restrict__ bias = ptrs.bias[z];
    u16* __restrict__ Cout = ptrs.out[z];

    const int tid  = threadIdx.x;
    const int wave = tid >> 6, lane = tid & 63;
    const int quad = lane >> 4, l16 = lane & 15;
    const int wrow = wave >> 2, wcol = wave & 3;          // 2 x 4 wave grid
    const int bm = blockIdx.x * 256;
    const int bn = blockIdx.y * 256;

    // ---- staging source (inverse-permuted global col, linear LDS dest) ----
    const int coloff = (((tid & 7) ^ ((tid >> 3) & 7)) * 8);   // elems
    const u16* srcA = A + (size_t)(bm + (tid >> 3)) * DD + coloff;
    const u16* srcB = W + (size_t)(bn + (tid >> 3)) * DD + coloff;

    #define STAGE_A(T,H) do{ \
        u16* _d = &lds[(((T)&1)*2 + (H))*8192 + tid*8]; \
        const u16* _g = srcA + (size_t)(H)*128*DD + (size_t)(((T)&15)*64); \
        g2l16(_g, _d); g2l16(_g + (size_t)64*DD, _d + 4096); }while(0)
    #define STAGE_B(T,H) do{ \
        u16* _d = &lds[32768 + (((T)&1)*2 + (H))*8192 + tid*8]; \
        const u16* _g = srcB + (size_t)(H)*128*DD + (size_t)(((T)&15)*64); \
        g2l16(_g, _d); g2l16(_g + (size_t)64*DD, _d + 4096); }while(0)

    // ---- fragment read bases (swizzled); kk=0 oct=quad, kk=1 oct=quad+4 ----
    const u32 lbase = lds_u32(&lds[0]);
    const u32 rowb  = (u32)(l16 * 128);
    const u32 sw0   = (u32)(((quad    ) ^ (l16 & 7)) << 4);
    const u32 sw1   = (u32)(((quad + 4) ^ (l16 & 7)) << 4);
    u32 addr_a0 = lbase + (u32)(wrow * 8192) + rowb + sw0;
    u32 addr_a1 = lbase + (u32)(wrow * 8192) + rowb + sw1;
    u32 addr_b0 = lbase + 65536u + (u32)(wcol * 4096) + rowb + sw0;
    u32 addr_b1 = lbase + 65536u + (u32)(wcol * 4096) + rowb + sw1;

    floatx4 acc[8][4];
    #pragma unroll
    for (int i = 0; i < 8; i++)
        #pragma unroll
        for (int j = 0; j < 4; j++)
            acc[i][j] = (floatx4){0.f, 0.f, 0.f, 0.f};

    // ---- prologue: tile-0 fully + tile-1 h0 halves; drain tile-0; pre-read q00 frags ----
    STAGE_A(0,0); STAGE_B(0,0); STAGE_B(0,1); STAGE_A(0,1); STAGE_A(1,0); STAGE_B(1,0);
    VM4(); BAR();                         // tile-0 halves landed; {Ah0(1),Bh0(1)} in flight
    bf16x8 af0[8], af1[8], bf0[4], bf1[4];
    rd_a8<0>(af0, addr_a0, addr_a1);      // pre-read A0(0), B0(0)
    rd_b4<0>(bf0, addr_b0, addr_b1);

    for (int t = 0; t < 16; ++t){
        // ---- Phase A: q00, q01 ----
        STAGE_B(t+1, 1);
        BAR();
        LGKM0(); SB0();                               // A0,B0 of tile t ready
        PRIO1(); mm8<0,0>(acc, af0, bf0); PRIO0(); SB0();
        rd_b4<16384>(bf1, addr_b0, addr_b1);          // B1 of tile t (drains under q00... q01 wait)
        STAGE_A(t+1, 1);
        LGKM0(); SB0();                               // B1 ready
        PRIO1(); mm8<0,1>(acc, af0, bf1); PRIO0(); SB0();
        rd_a8<16384>(af1, addr_a0, addr_a1);          // A1 of tile t
        VM4(); BAR();                                 // Ah0(t+1),Bh0(t+1) landed
        // ---- Phase B: q10, q11 ----
        STAGE_A(t+2, 0);
        BAR();
        LGKM0(); SB0();                               // A1 ready
        PRIO1(); mm8<1,0>(acc, af1, bf0); PRIO0(); SB0();
        rd_a8<0>(af0, addr_a0 ^ 32768u, addr_a1 ^ 32768u);   // read-ahead: q00 frags of t+1
        rd_b4<0>(bf0, addr_b0 ^ 32768u, addr_b1 ^ 32768u);
        STAGE_B(t+2, 0);
        PRIO1(); mm8<1,1>(acc, af1, bf1); PRIO0(); SB0();    // no wait: frags in regs
        VM4(); BAR();                                 // Bh1(t+1),Ah1(t+1) landed
        addr_a0 ^= 32768u; addr_a1 ^= 32768u;
        addr_b0 ^= 32768u; addr_b1 ^= 32768u;
    }
    asm volatile("s_waitcnt vmcnt(0) lgkmcnt(0)" ::: "memory");  // retire dead tail reads

    #undef STAGE_A
    #undef STAGE_B

    // ---- epilogue ----
    float bj[4];
    #pragma unroll
    for (int j = 0; j < 4; j++)
        bj[j] = bias[bn + (j >= 2 ? 128 : 0) + wcol * 32 + (j & 1) * 16 + l16];

    #pragma unroll
    for (int i = 0; i < 8; i++){
        const int row0 = bm + (i >= 4 ? 128 : 0) + wrow * 64 + (i & 3) * 16 + quad * 4;
        #pragma unroll
        for (int j = 0; j < 4; j++){
            const int col = bn + (j >= 2 ? 128 : 0) + wcol * 32 + (j & 1) * 16 + l16;
            #pragma unroll
            for (int r = 0; r < 4; r++){
                size_t idx = (size_t)(row0 + r) * DD + col;
                float zv = acc[i][j][r] + bj[j];
                if (MODE == 0){
                    Cout[idx] = f2b(zv);
                } else {
                    float sl = zv * sigf(zv);            // silu(dhat)
                    dout[idx] = xres[idx] + sigf(sl) * zv;
                }
            }
        }
    }
}

// ---------------- fused middle: block per row, 4 elems/thread (VGPR-light) ----------------
// XCD-locality swizzle (T1): row = (bid&7)*2048 + (bid>>3). Blocks round-robin across
// 8 XCDs by bid; this gives each XCD a contiguous 2048-row band, so the conv's
// t-1/t/t+1 re-reads of q0/k0/v0 hit that XCD's L2 instead of re-fetching HBM.
// Pure bijective relabeling (16384 % 8 == 0) -- correctness unaffected (G16).
__global__ __launch_bounds__(256) void mid_fuse(
    const u16* __restrict__ q0, const u16* __restrict__ k0, const u16* __restrict__ v0,
    const u16* __restrict__ a0, const u16* __restrict__ b0,
    const float* __restrict__ wcT,     // [3 streams][3 taps][1024]
    const float* __restrict__ bqc, const float* __restrict__ bkc, const float* __restrict__ bvc,
    const float* __restrict__ g2, u16* __restrict__ uout)
{
    __shared__ float red[8];
    const int bid = blockIdx.x;
    const int row = ((bid & 7) << 11) | (bid >> 3);
    const int t   = row & (TT - 1);
    const int tid = threadIdx.x;
    const int d0  = tid * 4;
    const size_t base = (size_t)row * DD + d0;
    const bool hm = (t > 0), hp = (t < TT - 1);

    float q[4], k[4], v[4];
    {
        const u16*   srcs[3] = {q0, k0, v0};
        const float* bs[3]   = {bqc, bkc, bvc};
        float* outs[3]       = {q, k, v};
        #pragma unroll
        for (int s = 0; s < 3; s++){
            float cm[4], cc[4], cp[4];
            load4bf(srcs[s] + base, cc);
            if (hm) load4bf(srcs[s] + base - DD, cm);
            else { cm[0]=0.f; cm[1]=0.f; cm[2]=0.f; cm[3]=0.f; }
            if (hp) load4bf(srcs[s] + base + DD, cp);
            else { cp[0]=0.f; cp[1]=0.f; cp[2]=0.f; cp[3]=0.f; }
            const float* wt = wcT + s * 3 * DD + d0;
            const float* bb = bs[s] + d0;
            #pragma unroll
            for (int j = 0; j < 4; j++){
                float y = cm[j] * wt[j] + cc[j] * wt[DD + j] + cp[j] * wt[2 * DD + j] + bb[j];
                outs[s][j] = sigf(y);
            }
        }
    }

    float sq = 0.f, sk = 0.f;
    #pragma unroll
    for (int j = 0; j < 4; j++){ sq += q[j] * q[j]; sk += k[j] * k[j]; }
    block_reduce2(sq, sk, red, tid);
    const float rq = rsqrtf(sq + 1e-8f), rk = rsqrtf(sk + 1e-8f);

    float av[4], bv[4];
    load4bf(a0 + base, av);
    load4bf(b0 + base, bv);

    float dl[4], s1 = 0.f, s2 = 0.f;
    #pragma unroll
    for (int j = 0; j < 4; j++){
        float d = (q[j] * rq) * (k[j] * rk) * v[j];
        d = tanhfast(av[j]) * d + bv[j];
        dl[j] = d; s1 += d; s2 += d * d;
    }
    block_reduce2(s1, s2, red, tid);
    const float mu = s1 * (1.0f / DD);
    const float ms = fmaxf(s2 * (1.0f / DD) - mu * mu, 0.0f);
    const float sc = rsqrtf(ms + 1e-8f);

    u16x4 ov;
    ov.x = f2b((dl[0] - mu) * sc * g2[d0 + 0]);
    ov.y = f2b((dl[1] - mu) * sc * g2[d0 + 1]);
    ov.z = f2b((dl[2] - mu) * sc * g2[d0 + 2]);
    ov.w = f2b((dl[3] - mu) * sc * g2[d0 + 3]);
    *(u16x4*)(uout + base) = ov;
}

extern "C" void kernel_launch(void* const* d_in, const int* in_sizes, int n_in,
                              void* d_out, int out_size, void* d_ws, size_t ws_size,
                              hipStream_t stream)
{
    const float* x   = (const float*)d_in[0];
    const float* g1  = (const float*)d_in[1];
    const float* Wq  = (const float*)d_in[2];
    const float* bq  = (const float*)d_in[3];
    const float* Wk  = (const float*)d_in[4];
    const float* bk  = (const float*)d_in[5];
    const float* Wv  = (const float*)d_in[6];
    const float* bv  = (const float*)d_in[7];
    const float* wqc = (const float*)d_in[8];
    const float* bqc = (const float*)d_in[9];
    const float* wkc = (const float*)d_in[10];
    const float* bkc = (const float*)d_in[11];
    const float* wvc = (const float*)d_in[12];
    const float* bvc = (const float*)d_in[13];
    const float* Wa  = (const float*)d_in[14];
    const float* ba  = (const float*)d_in[15];
    const float* Wb  = (const float*)d_in[16];
    const float* bb  = (const float*)d_in[17];
    const float* g2  = (const float*)d_in[18];
    const float* Wp  = (const float*)d_in[19];
    const float* bp  = (const float*)d_in[20];

    u16* ws = (u16*)d_ws;
    const size_t WSZ = (size_t)DD * DD;      // 1M elements
    const size_t TSZ = (size_t)MM * DD;      // 16.78M elements
    u16* WT = ws;                             // 6 transposed bf16 weights (q,k,v,a,b,p)
    float* wcT = (float*)(ws + 6 * WSZ);      // 3*3*1024 fp32 conv weights, transposed
    u16* xb = ws + 6 * WSZ + 32768;           // bf16 copy of x (64KB gap holds wcT)
    u16* h  = xb + TSZ;
    u16* q0 = h  + TSZ;
    u16* k0 = q0 + TSZ;
    u16* v0 = k0 + TSZ;
    u16* a0 = v0 + TSZ;
    u16* b0 = a0 + TSZ;
    u16* u  = h;                              // h dead after GEMM stage; reuse for u

    transpose_w<<<dim3(32, 32, 6), dim3(32, 8, 1), 0, stream>>>(Wq, Wk, Wv, Wa, Wb, Wp, WT);
    prep_wc<<<dim3(9), dim3(256), 0, stream>>>(wqc, wkc, wvc, wcT);
    prep_rows<<<dim3(MM / 4), dim3(256), 0, stream>>>(x, g1, xb, h);

    GemmPtrs p0;
    p0.A[0] = h;  p0.W[0] = WT + 0 * WSZ; p0.bias[0] = bq; p0.out[0] = q0;
    p0.A[1] = h;  p0.W[1] = WT + 1 * WSZ; p0.bias[1] = bk; p0.out[1] = k0;
    p0.A[2] = h;  p0.W[2] = WT + 2 * WSZ; p0.bias[2] = bv; p0.out[2] = v0;
    p0.A[3] = xb; p0.W[3] = WT + 3 * WSZ; p0.bias[3] = ba; p0.out[3] = a0;
    p0.A[4] = xb; p0.W[4] = WT + 4 * WSZ; p0.bias[4] = bb; p0.out[4] = b0;
    gemm_bf16<0><<<dim3(64, 4, 5), dim3(512), 0, stream>>>(p0, nullptr, nullptr);

    mid_fuse<<<dim3(MM), dim3(256), 0, stream>>>(q0, k0, v0, a0, b0,
                                                 wcT, bqc, bkc, bvc, g2, u);

    GemmPtrs p1;
    for (int i = 0; i < 5; i++){ p1.A[i] = u; p1.W[i] = WT + 5 * WSZ; p1.bias[i] = bp; p1.out[i] = nullptr; }
    gemm_bf16<1><<<dim3(64, 4, 1), dim3(512), 0, stream>>>(p1, x, (float*)d_out);
}

// Round 9
// 448.287 us; speedup vs baseline: 1.0281x; 1.0281x over previous
//
#include <hip/hip_runtime.h>
#include <stdint.h>

#define DD 1024
#define TT 2048
#define BBATCH 8
#define MM (BBATCH*TT)   // 16384 rows

typedef unsigned short u16;
typedef unsigned int   u32;

typedef __attribute__((ext_vector_type(8))) __bf16 bf16x8;
typedef __attribute__((ext_vector_type(4))) float  floatx4;
typedef __attribute__((ext_vector_type(4))) unsigned short u16x4;
typedef __attribute__((ext_vector_type(8))) unsigned short u16x8;
typedef __attribute__((ext_vector_type(4))) unsigned int   u32x4;

__device__ __forceinline__ float b2f(u16 v){
    u32 x = ((u32)v) << 16;
    return __builtin_bit_cast(float, x);
}
__device__ __forceinline__ u16 f2b(float f){
    u32 u = __builtin_bit_cast(u32, f);
    u32 r = (u + 0x7fffu + ((u >> 16) & 1u)) >> 16;
    return (u16)r;
}
__device__ __forceinline__ float sigf(float x){
    return 1.0f / (1.0f + __expf(-x));
}
__device__ __forceinline__ float tanhfast(float x){
    float e = __expf(2.0f * x);          // inf for big x -> 1.0 (correct limit)
    return 1.0f - 2.0f / (e + 1.0f);
}

// async global->LDS, 16B per lane. LDS dest = wave-uniform base + lane*16.
__device__ __forceinline__ void g2l16(const u16* g, u16* l){
    __builtin_amdgcn_global_load_lds(
        (const __attribute__((address_space(1))) u32*)g,
        (__attribute__((address_space(3))) u32*)l, 16, 0, 0);
}

__device__ __forceinline__ u32 lds_u32(const u16* p){
    return (u32)(size_t)(const __attribute__((address_space(3))) u16*)p;
}

// inline-asm LDS read: compiler does not model the load, so explicit
// lgkmcnt(0)+sched_barrier(0) fencing is mandatory before consuming (rule #18).
template<int OFF>
__device__ __forceinline__ bf16x8 dsr(u32 addr){
    u32x4 d;
    asm volatile("ds_read_b128 %0, %1 offset:%2" : "=v"(d) : "v"(addr), "i"(OFF));
    return __builtin_bit_cast(bf16x8, d);
}

// kk (k-half) lives in separate base registers a0/a1: the bank swizzle XOR
// occupies byte bits 4-6, which an immediate +64 offset would corrupt.
template<int BASE>
__device__ __forceinline__ void rd_a8(bf16x8 (&arr)[8], u32 a0, u32 a1){
    arr[0]=dsr<BASE+0>(a0);    arr[1]=dsr<BASE+0>(a1);
    arr[2]=dsr<BASE+2048>(a0); arr[3]=dsr<BASE+2048>(a1);
    arr[4]=dsr<BASE+4096>(a0); arr[5]=dsr<BASE+4096>(a1);
    arr[6]=dsr<BASE+6144>(a0); arr[7]=dsr<BASE+6144>(a1);
}
template<int BASE>
__device__ __forceinline__ void rd_b4(bf16x8 (&arr)[4], u32 a0, u32 a1){
    arr[0]=dsr<BASE+0>(a0);    arr[1]=dsr<BASE+0>(a1);
    arr[2]=dsr<BASE+2048>(a0); arr[3]=dsr<BASE+2048>(a1);
}

__device__ __forceinline__ void load4bf(const u16* p, float* o){
    u16x4 v = *(const u16x4*)p;
    o[0] = b2f(v.x); o[1] = b2f(v.y); o[2] = b2f(v.z); o[3] = b2f(v.w);
}

__device__ __forceinline__ void wave_reduce2(float& a, float& b){
    #pragma unroll
    for (int m = 32; m; m >>= 1){
        a += __shfl_xor(a, m, 64);
        b += __shfl_xor(b, m, 64);
    }
}

// 7-value block reduction, one LDS round. Leading barrier protects red reuse.
__device__ __forceinline__ void block_reduce7(float* v, float* red, int tid){
    #pragma unroll
    for (int off = 32; off; off >>= 1){
        #pragma unroll
        for (int i = 0; i < 7; i++)
            v[i] += __shfl_down(v[i], off, 64);
    }
    __syncthreads();
    if ((tid & 63) == 0){
        #pragma unroll
        for (int i = 0; i < 7; i++) red[(tid >> 6) * 8 + i] = v[i];
    }
    __syncthreads();
    #pragma unroll
    for (int i = 0; i < 7; i++)
        v[i] = red[i] + red[8 + i] + red[16 + i] + red[24 + i];
}

// ---------------- merged prep: weight transpose + conv-w transpose + row prep ----------------
// blocks [0,6144): transpose 6 x [1024,1024] fp32 -> bf16 [N,K]
// blocks [6144,6153): conv weights [1024,3] -> [3][1024] x 3 streams
// blocks [6153,10249): x -> bf16 copy (xb) + zc_rms(x,g1) -> h, one row per wave
__global__ __launch_bounds__(256) void prep_all(
    const float* __restrict__ s0, const float* __restrict__ s1, const float* __restrict__ s2,
    const float* __restrict__ s3, const float* __restrict__ s4, const float* __restrict__ s5,
    u16* __restrict__ WT,
    const float* __restrict__ w0, const float* __restrict__ w1, const float* __restrict__ w2,
    float* __restrict__ wcT,
    const float* __restrict__ x, const float* __restrict__ g1,
    u16* __restrict__ xb, u16* __restrict__ h)
{
    __shared__ u16 tile[32][33];
    const int bid = blockIdx.x;
    const int tid = threadIdx.x;

    if (bid < 6144){
        const float* srcs[6] = {s0, s1, s2, s3, s4, s5};
        const int z  = bid >> 10;
        const int bi = bid & 1023;
        const int bx = bi & 31, by = bi >> 5;
        const float* src = srcs[z];
        u16* dst = WT + (size_t)z * (DD * (size_t)DD);
        const int tx = tid & 31, ty = tid >> 5;
        #pragma unroll
        for (int i = 0; i < 4; i++){
            int y = by * 32 + ty + i * 8;
            tile[ty + i * 8][tx] = f2b(src[(size_t)y * DD + bx * 32 + tx]);
        }
        __syncthreads();
        #pragma unroll
        for (int i = 0; i < 4; i++){
            int y2 = bx * 32 + ty + i * 8;
            dst[(size_t)y2 * DD + by * 32 + tx] = tile[tx][ty + i * 8];
        }
        return;
    }
    if (bid < 6153){
        const float* srcs[3] = {w0, w1, w2};
        const int b = bid - 6144;
        const int s = b / 3, tap = b % 3;
        #pragma unroll
        for (int i = 0; i < 4; i++){
            int d = tid + i * 256;
            wcT[(s * 3 + tap) * DD + d] = srcs[s][d * 3 + tap];
        }
        return;
    }

    // ---- prep_rows ----
    const int w = tid >> 6, lane = tid & 63;
    const int row = (bid - 6153) * 4 + w;
    const int d0 = lane * 16;
    const size_t base = (size_t)row * DD + d0;

    float v[16];
    #pragma unroll
    for (int c = 0; c < 4; c++){
        floatx4 t = *(const floatx4*)(x + base + c * 4);
        v[c*4+0] = t.x; v[c*4+1] = t.y; v[c*4+2] = t.z; v[c*4+3] = t.w;
    }
    u16x8 x0, x1;
    #pragma unroll
    for (int j = 0; j < 8; j++){ x0[j] = f2b(v[j]); x1[j] = f2b(v[8+j]); }
    *(u16x8*)(xb + base)     = x0;
    *(u16x8*)(xb + base + 8) = x1;

    float p1 = 0.f, p2 = 0.f;
    #pragma unroll
    for (int j = 0; j < 16; j++){ p1 += v[j]; p2 += v[j]*v[j]; }
    wave_reduce2(p1, p2);
    const float mu = p1 * (1.0f / DD);
    const float ms = fmaxf(p2 * (1.0f / DD) - mu * mu, 0.0f);
    const float sc = rsqrtf(ms + 1e-8f);

    u16x8 o0, o1;
    #pragma unroll
    for (int j = 0; j < 8; j++)  o0[j] = f2b((v[j]     - mu) * sc * g1[d0 + j]);
    #pragma unroll
    for (int j = 0; j < 8; j++)  o1[j] = f2b((v[8 + j] - mu) * sc * g1[d0 + 8 + j]);
    *(u16x8*)(h + base)     = o0;
    *(u16x8*)(h + base + 8) = o1;
}

// ---------------- GEMM: C[M,N] = A[M,K](bf16) * W^T[N,K](bf16)^T + bias(fp32) ----------------
// VERIFIED r5/r8 structure (gemm<0> 165 us, conflicts = 0).
// 256x256 tile, BK=64, 512 thr (8 waves 2Mx4N), per-wave 128x64 out.
// Conflict-free swizzle: phys_byte = logical ^ ((row&7)<<4).
// READ-AHEAD pipeline: each fragment group ds_read one MFMA-quadrant EARLY:
//   PhaseA: [A0,B0 pre-read last tile] q00; read B1; q01; read A1;   VM4+BAR
//   PhaseB: q10; read-ahead A0',B0' (tile t+1, other parity buffer); q11; VM4+BAR
// Staging: PA stages Bh1(t+1), Ah1(t+1); PB stages Ah0(t+2), Bh0(t+2).
// vmcnt(4) at PA-end drains Ah0(t+1),Bh0(t+1); vmcnt(4) at PB-end drains Bh1/Ah1(t+1).
struct GemmPtrs {
    const u16*   A[5];
    const u16*   W[5];     // transposed weights, [N,K] row-major, bf16
    const float* bias[5];
    u16*         out[5];
};

#define BAR()   asm volatile("s_barrier" ::: "memory")
#define LGKM0() asm volatile("s_waitcnt lgkmcnt(0)" ::: "memory")
#define VM4()   asm volatile("s_waitcnt vmcnt(4)" ::: "memory")
#define SB0()   __builtin_amdgcn_sched_barrier(0)
#define PRIO1() __builtin_amdgcn_s_setprio(1)
#define PRIO0() __builtin_amdgcn_s_setprio(0)

template<int IH, int JH>
__device__ __forceinline__ void mm8(floatx4 (&acc)[8][4], const bf16x8 (&af)[8], const bf16x8 (&bf)[4]){
    #pragma unroll
    for (int kk = 0; kk < 2; kk++)
        #pragma unroll
        for (int i = 0; i < 4; i++)
            #pragma unroll
            for (int j = 0; j < 2; j++)
                acc[IH*4+i][JH*2+j] = __builtin_amdgcn_mfma_f32_16x16x32_bf16(
                    af[i*2+kk], bf[j*2+kk], acc[IH*4+i][JH*2+j], 0, 0, 0);
}

template<int MODE>   // 0: store bf16(A*W+bias) ; 1: fp32 epilogue with residual
__global__ __launch_bounds__(512, 2) void gemm_bf16(
    GemmPtrs ptrs, const float* __restrict__ xres, float* __restrict__ dout)
{
    __shared__ alignas(16) u16 lds[65536];        // 128 KB: A 0..64KB, B 64..128KB

    const int z = blockIdx.z;
    const u16*   __restrict__ A    = ptrs.A[z];
    const u16*   __restrict__ W    = ptrs.W[z];
    const float* __restrict__ bias = ptrs.bias[z];
    u16* __restrict__ Cout = ptrs.out[z];

    const int tid  = threadIdx.x;
    const int wave = tid >> 6, lane = tid & 63;
    const int quad = lane >> 4, l16 = lane & 15;
    const int wrow = wave >> 2, wcol = wave & 3;          // 2 x 4 wave grid
    const int bm = blockIdx.x * 256;
    const int bn = blockIdx.y * 256;

    // ---- staging source (inverse-permuted global col, linear LDS dest) ----
    const int coloff = (((tid & 7) ^ ((tid >> 3) & 7)) * 8);   // elems
    const u16* srcA = A + (size_t)(bm + (tid >> 3)) * DD + coloff;
    const u16* srcB = W + (size_t)(bn + (tid >> 3)) * DD + coloff;

    #define STAGE_A(T,H) do{ \
        u16* _d = &lds[(((T)&1)*2 + (H))*8192 + tid*8]; \
        const u16* _g = srcA + (size_t)(H)*128*DD + (size_t)(((T)&15)*64); \
        g2l16(_g, _d); g2l16(_g + (size_t)64*DD, _d + 4096); }while(0)
    #define STAGE_B(T,H) do{ \
        u16* _d = &lds[32768 + (((T)&1)*2 + (H))*8192 + tid*8]; \
        const u16* _g = srcB + (size_t)(H)*128*DD + (size_t)(((T)&15)*64); \
        g2l16(_g, _d); g2l16(_g + (size_t)64*DD, _d + 4096); }while(0)

    // ---- fragment read bases (swizzled); kk=0 oct=quad, kk=1 oct=quad+4 ----
    const u32 lbase = lds_u32(&lds[0]);
    const u32 rowb  = (u32)(l16 * 128);
    const u32 sw0   = (u32)(((quad    ) ^ (l16 & 7)) << 4);
    const u32 sw1   = (u32)(((quad + 4) ^ (l16 & 7)) << 4);
    u32 addr_a0 = lbase + (u32)(wrow * 8192) + rowb + sw0;
    u32 addr_a1 = lbase + (u32)(wrow * 8192) + rowb + sw1;
    u32 addr_b0 = lbase + 65536u + (u32)(wcol * 4096) + rowb + sw0;
    u32 addr_b1 = lbase + 65536u + (u32)(wcol * 4096) + rowb + sw1;

    floatx4 acc[8][4];
    #pragma unroll
    for (int i = 0; i < 8; i++)
        #pragma unroll
        for (int j = 0; j < 4; j++)
            acc[i][j] = (floatx4){0.f, 0.f, 0.f, 0.f};

    // ---- prologue: tile-0 fully + tile-1 h0 halves; drain tile-0; pre-read q00 frags ----
    STAGE_A(0,0); STAGE_B(0,0); STAGE_B(0,1); STAGE_A(0,1); STAGE_A(1,0); STAGE_B(1,0);
    VM4(); BAR();                         // tile-0 halves landed; {Ah0(1),Bh0(1)} in flight
    bf16x8 af0[8], af1[8], bf0[4], bf1[4];
    rd_a8<0>(af0, addr_a0, addr_a1);      // pre-read A0(0), B0(0)
    rd_b4<0>(bf0, addr_b0, addr_b1);

    for (int t = 0; t < 16; ++t){
        // ---- Phase A: q00, q01 ----
        STAGE_B(t+1, 1);
        BAR();
        LGKM0(); SB0();                               // A0,B0 of tile t ready
        PRIO1(); mm8<0,0>(acc, af0, bf0); PRIO0(); SB0();
        rd_b4<16384>(bf1, addr_b0, addr_b1);          // B1 of tile t (drains under q00... q01 wait)
        STAGE_A(t+1, 1);
        LGKM0(); SB0();                               // B1 ready
        PRIO1(); mm8<0,1>(acc, af0, bf1); PRIO0(); SB0();
        rd_a8<16384>(af1, addr_a0, addr_a1);          // A1 of tile t
        VM4(); BAR();                                 // Ah0(t+1),Bh0(t+1) landed
        // ---- Phase B: q10, q11 ----
        STAGE_A(t+2, 0);
        BAR();
        LGKM0(); SB0();                               // A1 ready
        PRIO1(); mm8<1,0>(acc, af1, bf0); PRIO0(); SB0();
        rd_a8<0>(af0, addr_a0 ^ 32768u, addr_a1 ^ 32768u);   // read-ahead: q00 frags of t+1
        rd_b4<0>(bf0, addr_b0 ^ 32768u, addr_b1 ^ 32768u);
        STAGE_B(t+2, 0);
        PRIO1(); mm8<1,1>(acc, af1, bf1); PRIO0(); SB0();    // no wait: frags in regs
        VM4(); BAR();                                 // Bh1(t+1),Ah1(t+1) landed
        addr_a0 ^= 32768u; addr_a1 ^= 32768u;
        addr_b0 ^= 32768u; addr_b1 ^= 32768u;
    }
    asm volatile("s_waitcnt vmcnt(0) lgkmcnt(0)" ::: "memory");  // retire dead tail reads

    #undef STAGE_A
    #undef STAGE_B

    // ---- epilogue ----
    float bj[4];
    #pragma unroll
    for (int j = 0; j < 4; j++)
        bj[j] = bias[bn + (j >= 2 ? 128 : 0) + wcol * 32 + (j & 1) * 16 + l16];

    #pragma unroll
    for (int i = 0; i < 8; i++){
        const int row0 = bm + (i >= 4 ? 128 : 0) + wrow * 64 + (i & 3) * 16 + quad * 4;
        #pragma unroll
        for (int j = 0; j < 4; j++){
            const int col = bn + (j >= 2 ? 128 : 0) + wcol * 32 + (j & 1) * 16 + l16;
            #pragma unroll
            for (int r = 0; r < 4; r++){
                size_t idx = (size_t)(row0 + r) * DD + col;
                float zv = acc[i][j][r] + bj[j];
                if (MODE == 0){
                    Cout[idx] = f2b(zv);
                } else {
                    float sl = zv * sigf(zv);            // silu(dhat)
                    dout[idx] = xres[idx] + sigf(sl) * zv;
                }
            }
        }
    }
}

// ---------------- fused middle v2: 8 rows per block, sliding conv window ----------------
// Latency-oriented rewrite: 2048 blocks (8x fewer), each q/k/v row loaded ONCE
// (register slide cm<-cc<-cp), next-row loads issued BEFORE the reduction so HBM
// latency hides under it. Single reduction round per row via moment rearrangement:
//   d = C*w + b,  w = tanh(a)*q*k*v,  C = rq*rk  (C-independent sums:
//   sq, sk, W1=Σw, W2=Σw², WB=Σwb, B1=Σb, B2=Σb²  -> 7-sum single block_reduce;
//   s1 = C*W1+B1,  s2 = C²*W2+2C*WB+B2).
// 2048 % 8 == 0 so a block never straddles a batch boundary.
__global__ __launch_bounds__(256) void mid_fuse(
    const u16* __restrict__ q0, const u16* __restrict__ k0, const u16* __restrict__ v0,
    const u16* __restrict__ a0, const u16* __restrict__ b0,
    const float* __restrict__ wcT,     // [3 streams][3 taps][1024]
    const float* __restrict__ bqc, const float* __restrict__ bkc, const float* __restrict__ bvc,
    const float* __restrict__ g2, u16* __restrict__ uout)
{
    __shared__ float red[32];
    const int tid = threadIdx.x;
    const int d0  = tid * 4;
    const int r0  = blockIdx.x * 8;
    const int t0  = r0 & (TT - 1);
    const u16* srcs[3] = {q0, k0, v0};
    const float* bsrc[3] = {bqc, bkc, bvc};

    // conv weights/biases/gain resident in regs (tiny, read once per block)
    float wt[3][3][4], cb[3][4], gv[4];
    #pragma unroll
    for (int s = 0; s < 3; s++){
        #pragma unroll
        for (int p = 0; p < 3; p++){
            const float* wp = wcT + (s * 3 + p) * DD + d0;
            #pragma unroll
            for (int j = 0; j < 4; j++) wt[s][p][j] = wp[j];
        }
        #pragma unroll
        for (int j = 0; j < 4; j++) cb[s][j] = bsrc[s][d0 + j];
    }
    #pragma unroll
    for (int j = 0; j < 4; j++) gv[j] = g2[d0 + j];

    const size_t base = (size_t)r0 * DD + d0;

    float cm[3][4], cc[3][4], cp[3][4], av[4], bv[4];
    #pragma unroll
    for (int s = 0; s < 3; s++){
        if (t0 > 0) load4bf(srcs[s] + base - DD, cm[s]);
        else { cm[s][0]=0.f; cm[s][1]=0.f; cm[s][2]=0.f; cm[s][3]=0.f; }
        load4bf(srcs[s] + base,      cc[s]);
        load4bf(srcs[s] + base + DD, cp[s]);     // t0+1 <= 2041 always valid
    }
    load4bf(a0 + base, av);
    load4bf(b0 + base, bv);

    #pragma unroll
    for (int r = 0; r < 8; r++){
        const size_t rb = base + (size_t)r * DD;

        float q[4], k[4], v[4];
        float* outs[3] = {q, k, v};
        #pragma unroll
        for (int s = 0; s < 3; s++){
            #pragma unroll
            for (int j = 0; j < 4; j++){
                float y = cm[s][j] * wt[s][0][j] + cc[s][j] * wt[s][1][j]
                        + cp[s][j] * wt[s][2][j] + cb[s][j];
                outs[s][j] = sigf(y);
            }
        }

        float w4[4], p[7];
        p[0]=0.f; p[1]=0.f; p[2]=0.f; p[3]=0.f; p[4]=0.f; p[5]=0.f; p[6]=0.f;
        #pragma unroll
        for (int j = 0; j < 4; j++){
            float ww = tanhfast(av[j]) * q[j] * k[j] * v[j];
            w4[j] = ww;
            p[0] += q[j] * q[j];
            p[1] += k[j] * k[j];
            p[2] += ww;
            p[3] += ww * ww;
            p[4] += ww * bv[j];
            p[5] += bv[j];
            p[6] += bv[j] * bv[j];
        }

        // prefetch next row inputs; latency hides under the reduction below
        float cpn[3][4], avn[4], bvn[4];
        if (r < 7){
            const size_t nb = rb + DD;
            const bool hv = (t0 + r + 2) <= (TT - 1);
            #pragma unroll
            for (int s = 0; s < 3; s++){
                if (hv) load4bf(srcs[s] + nb + DD, cpn[s]);
                else { cpn[s][0]=0.f; cpn[s][1]=0.f; cpn[s][2]=0.f; cpn[s][3]=0.f; }
            }
            load4bf(a0 + nb, avn);
            load4bf(b0 + nb, bvn);

            block_reduce7(p, red, tid);

            const float rq = rsqrtf(p[0] + 1e-8f);
            const float rk = rsqrtf(p[1] + 1e-8f);
            const float C  = rq * rk;
            const float ss1 = C * p[2] + p[5];
            const float ss2 = C * C * p[3] + 2.0f * C * p[4] + p[6];
            const float mu = ss1 * (1.0f / DD);
            const float ms = fmaxf(ss2 * (1.0f / DD) - mu * mu, 0.0f);
            const float sc = rsqrtf(ms + 1e-8f);
            u16x4 ov;
            ov.x = f2b((C * w4[0] + bv[0] - mu) * sc * gv[0]);
            ov.y = f2b((C * w4[1] + bv[1] - mu) * sc * gv[1]);
            ov.z = f2b((C * w4[2] + bv[2] - mu) * sc * gv[2]);
            ov.w = f2b((C * w4[3] + bv[3] - mu) * sc * gv[3]);
            *(u16x4*)(uout + rb) = ov;

            // slide window
            #pragma unroll
            for (int s = 0; s < 3; s++){
                #pragma unroll
                for (int j = 0; j < 4; j++){
                    cm[s][j] = cc[s][j]; cc[s][j] = cp[s][j]; cp[s][j] = cpn[s][j];
                }
            }
            #pragma unroll
            for (int j = 0; j < 4; j++){ av[j] = avn[j]; bv[j] = bvn[j]; }
        } else {
            block_reduce7(p, red, tid);

            const float rq = rsqrtf(p[0] + 1e-8f);
            const float rk = rsqrtf(p[1] + 1e-8f);
            const float C  = rq * rk;
            const float ss1 = C * p[2] + p[5];
            const float ss2 = C * C * p[3] + 2.0f * C * p[4] + p[6];
            const float mu = ss1 * (1.0f / DD);
            const float ms = fmaxf(ss2 * (1.0f / DD) - mu * mu, 0.0f);
            const float sc = rsqrtf(ms + 1e-8f);
            u16x4 ov;
            ov.x = f2b((C * w4[0] + bv[0] - mu) * sc * gv[0]);
            ov.y = f2b((C * w4[1] + bv[1] - mu) * sc * gv[1]);
            ov.z = f2b((C * w4[2] + bv[2] - mu) * sc * gv[2]);
            ov.w = f2b((C * w4[3] + bv[3] - mu) * sc * gv[3]);
            *(u16x4*)(uout + rb) = ov;
        }
    }
}

extern "C" void kernel_launch(void* const* d_in, const int* in_sizes, int n_in,
                              void* d_out, int out_size, void* d_ws, size_t ws_size,
                              hipStream_t stream)
{
    const float* x   = (const float*)d_in[0];
    const float* g1  = (const float*)d_in[1];
    const float* Wq  = (const float*)d_in[2];
    const float* bq  = (const float*)d_in[3];
    const float* Wk  = (const float*)d_in[4];
    const float* bk  = (const float*)d_in[5];
    const float* Wv  = (const float*)d_in[6];
    const float* bv  = (const float*)d_in[7];
    const float* wqc = (const float*)d_in[8];
    const float* bqc = (const float*)d_in[9];
    const float* wkc = (const float*)d_in[10];
    const float* bkc = (const float*)d_in[11];
    const float* wvc = (const float*)d_in[12];
    const float* bvc = (const float*)d_in[13];
    const float* Wa  = (const float*)d_in[14];
    const float* ba  = (const float*)d_in[15];
    const float* Wb  = (const float*)d_in[16];
    const float* bb  = (const float*)d_in[17];
    const float* g2  = (const float*)d_in[18];
    const float* Wp  = (const float*)d_in[19];
    const float* bp  = (const float*)d_in[20];

    u16* ws = (u16*)d_ws;
    const size_t WSZ = (size_t)DD * DD;      // 1M elements
    const size_t TSZ = (size_t)MM * DD;      // 16.78M elements
    u16* WT = ws;                             // 6 transposed bf16 weights (q,k,v,a,b,p)
    float* wcT = (float*)(ws + 6 * WSZ);      // 3*3*1024 fp32 conv weights, transposed
    u16* xb = ws + 6 * WSZ + 32768;           // bf16 copy of x (64KB gap holds wcT)
    u16* h  = xb + TSZ;
    u16* q0 = h  + TSZ;
    u16* k0 = q0 + TSZ;
    u16* v0 = k0 + TSZ;
    u16* a0 = v0 + TSZ;
    u16* b0 = a0 + TSZ;
    u16* u  = h;                              // h dead after GEMM stage; reuse for u

    prep_all<<<dim3(10249), dim3(256), 0, stream>>>(
        Wq, Wk, Wv, Wa, Wb, Wp, WT, wqc, wkc, wvc, wcT, x, g1, xb, h);

    GemmPtrs p0;
    p0.A[0] = h;  p0.W[0] = WT + 0 * WSZ; p0.bias[0] = bq; p0.out[0] = q0;
    p0.A[1] = h;  p0.W[1] = WT + 1 * WSZ; p0.bias[1] = bk; p0.out[1] = k0;
    p0.A[2] = h;  p0.W[2] = WT + 2 * WSZ; p0.bias[2] = bv; p0.out[2] = v0;
    p0.A[3] = xb; p0.W[3] = WT + 3 * WSZ; p0.bias[3] = ba; p0.out[3] = a0;
    p0.A[4] = xb; p0.W[4] = WT + 4 * WSZ; p0.bias[4] = bb; p0.out[4] = b0;
    gemm_bf16<0><<<dim3(64, 4, 5), dim3(512), 0, stream>>>(p0, nullptr, nullptr);

    mid_fuse<<<dim3(MM / 8), dim3(256), 0, stream>>>(q0, k0, v0, a0, b0,
                                                     wcT, bqc, bkc, bvc, g2, u);

    GemmPtrs p1;
    for (int i = 0; i < 5; i++){ p1.A[i] = u; p1.W[i] = WT + 5 * WSZ; p1.bias[i] = bp; p1.out[i] = nullptr; }
    gemm_bf16<1><<<dim3(64, 4, 1), dim3(512), 0, stream>>>(p1, x, (float*)d_out);
}